// Round 1
// baseline (532.532 us; speedup 1.0000x reference)
//
#include <hip/hip_runtime.h>
#include <hip/hip_bf16.h>
#include <math.h>

// LlamaStyleAttention: B=2, T=2048, C=2048, H=16, D=128, fp32 in/out.
// Pipeline: cast/transpose -> 3x GEMM(bf16 MFMA) -> RoPE -> flash attn -> GEMM.

#define TT 2048
#define CCn 2048
#define HH 16
#define DD 128
#define BBa 2
#define MMr 4096  // B*T

typedef __attribute__((ext_vector_type(8))) short s16x8;
typedef __attribute__((ext_vector_type(4))) short s16x4;
typedef __attribute__((ext_vector_type(4))) float f32x4;

__device__ __forceinline__ short bf16_of(float f) {
  unsigned u = __float_as_uint(f);
  unsigned r = u + 0x7fffu + ((u >> 16) & 1u);
  return (short)(r >> 16);
}

__device__ __forceinline__ void lds_load16(const void* g, void* l) {
  __builtin_amdgcn_global_load_lds((__attribute__((address_space(1))) void*)g,
                                   (__attribute__((address_space(3))) void*)l,
                                   16, 0, 0);
}

// ---------------- cos/sin tables: [T][64] fp32 ----------------
__global__ __launch_bounds__(256) void k_tables(float* __restrict__ cosT,
                                                float* __restrict__ sinT) {
  int idx = blockIdx.x * 256 + threadIdx.x;  // T*64 = 131072
  int t = idx >> 6, i = idx & 63;
  float inv = powf(10000.0f, -(float)i * (1.0f / 64.0f));
  float f = (float)t * inv;
  cosT[idx] = cosf(f);
  sinT[idx] = sinf(f);
}

// ---------------- x fp32 -> bf16 ----------------
__global__ __launch_bounds__(256) void k_cast_x(const float* __restrict__ x,
                                                short* __restrict__ xb) {
  int i = blockIdx.x * 256 + threadIdx.x;  // n/4 threads
  f32x4 v = ((const f32x4*)x)[i];
  s16x4 o;
#pragma unroll
  for (int j = 0; j < 4; ++j) o[j] = bf16_of(v[j]);
  ((s16x4*)xb)[i] = o;
}

// ---------------- weight transpose+cast: w[K][N] fp32 -> wt[N][K] bf16 ----------------
__global__ __launch_bounds__(256) void k_wtrans(const float* __restrict__ w,
                                                short* __restrict__ wt) {
  __shared__ float tile[32][33];
  int n0 = blockIdx.x * 32, k0 = blockIdx.y * 32;
  int tx = threadIdx.x & 31, ty = threadIdx.x >> 5;  // ty 0..7
#pragma unroll
  for (int j = 0; j < 4; ++j) {
    int k = ty * 4 + j;
    tile[k][tx] = w[(size_t)(k0 + k) * CCn + n0 + tx];
  }
  __syncthreads();
#pragma unroll
  for (int j = 0; j < 4; ++j) {
    int n = ty * 4 + j;
    wt[(size_t)(n0 + n) * CCn + k0 + tx] = bf16_of(tile[tx][n]);
  }
}

// ---------------- V transpose: tmp[B*T][C] fp32 -> Vt[B*H][D][T] bf16 ----------------
__global__ __launch_bounds__(256) void k_vtrans(const float* __restrict__ src,
                                                short* __restrict__ dst) {
  __shared__ float tile[32][33];
  int bh = blockIdx.y, b = bh >> 4, h = bh & 15;
  int dt = blockIdx.x & 3, tt = blockIdx.x >> 2;  // d-tile 0..3, t-tile 0..63
  int tx = threadIdx.x & 31, ty = threadIdx.x >> 5;
  const float* sp = src + ((size_t)(b * TT + tt * 32)) * CCn + h * DD + dt * 32;
#pragma unroll
  for (int j = 0; j < 4; ++j) {
    int tr = ty * 4 + j;
    tile[tr][tx] = sp[(size_t)tr * CCn + tx];  // tile[t_local][d_local]
  }
  __syncthreads();
  short* dp = dst + ((size_t)(bh * DD + dt * 32)) * TT + tt * 32;
#pragma unroll
  for (int j = 0; j < 4; ++j) {
    int dr = ty * 4 + j;
    dp[(size_t)dr * TT + tx] = bf16_of(tile[tx][dr]);
  }
}

// ---------------- RoPE + cast: tmp[B*T][C] fp32 -> dst[B*H][T][D] bf16 ----------------
__global__ __launch_bounds__(256) void k_rope(const float* __restrict__ src,
                                              const float* __restrict__ cosT,
                                              const float* __restrict__ sinT,
                                              short* __restrict__ dst) {
  int idx = blockIdx.x * 256 + threadIdx.x;  // B*T*H*64
  int i = idx & 63;
  int h = (idx >> 6) & 15;
  int t = (idx >> 10) & 2047;
  int b = idx >> 21;
  const float* row = src + ((size_t)(b * TT + t)) * CCn + h * DD;
  float q0 = row[i], q1 = row[i + 64];
  float c = cosT[t * 64 + i], s = sinT[t * 64 + i];
  short* orow = dst + ((size_t)((b * HH + h) * TT + t)) * DD;
  orow[i] = bf16_of(q0 * c - q1 * s);
  orow[i + 64] = bf16_of(q1 * c + q0 * s);
}

// ---------------- GEMM: C[M][N] = A[M][K]bf16 x Bt[N][K]bf16, fp32 out ----------------
// m97 structure: 128x128 tile, BK=64, 4 waves (2x2), 4x4 16x16 frags/wave.
#define BKG 64
__global__ __launch_bounds__(256) void k_gemm(const short* __restrict__ A,
                                              const short* __restrict__ Bt,
                                              float* __restrict__ Cc,
                                              int M, int N, int K) {
  __shared__ short As[128 * BKG];
  __shared__ short Bs[128 * BKG];
  const int tid = threadIdx.x, wid = tid >> 6, lane = tid & 63;
  const int wm = wid >> 1, wn = wid & 1;
  const int lr = lane & 15, lk = lane >> 4;
  const int m0 = blockIdx.y * 128, n0 = blockIdx.x * 128;

  f32x4 acc[4][4] = {};
  const int nk = K / BKG;
  for (int kt = 0; kt < nk; ++kt) {
#pragma unroll
    for (int it = 0; it < 4; ++it) {
      int ch = it * 256 + tid;
      int r = ch >> 3, c = (ch & 7) * 8;  // 8 chunks per 64-elem row
      lds_load16(A + (size_t)(m0 + r) * K + kt * BKG + c,
                 As + (size_t)(it * 256 + wid * 64) * 8);
      lds_load16(Bt + (size_t)(n0 + r) * K + kt * BKG + c,
                 Bs + (size_t)(it * 256 + wid * 64) * 8);
    }
    __syncthreads();
#pragma unroll
    for (int ks = 0; ks < 2; ++ks) {
      s16x8 af[4], bf[4];
#pragma unroll
      for (int i = 0; i < 4; ++i) {
        int ar = wm * 64 + i * 16 + lr;
        af[i] = *(const s16x8*)(As + ar * BKG + ks * 32 + lk * 8);
        int br = wn * 64 + i * 16 + lr;
        bf[i] = *(const s16x8*)(Bs + br * BKG + ks * 32 + lk * 8);
      }
#pragma unroll
      for (int i = 0; i < 4; ++i)
#pragma unroll
        for (int j = 0; j < 4; ++j)
          acc[i][j] = __builtin_amdgcn_mfma_f32_16x16x32_bf16(af[i], bf[j],
                                                              acc[i][j], 0, 0, 0);
    }
    __syncthreads();
  }
  // C layout: col=lane&15, row=(lane>>4)*4+reg  [m89-verified]
#pragma unroll
  for (int i = 0; i < 4; ++i)
#pragma unroll
    for (int j = 0; j < 4; ++j) {
      int col = n0 + wn * 64 + j * 16 + lr;
      int rb = m0 + wm * 64 + i * 16 + lk * 4;
#pragma unroll
      for (int r = 0; r < 4; ++r)
        Cc[(size_t)(rb + r) * N + col] = acc[i][j][r];
    }
}

// ---------------- Flash attention ----------------
// grid (T/64, B*H), 4 waves; wave w owns q rows [q0+16w, q0+16w+16).
// Swapped QK^T: mfma(K,Q) -> S^T with col=q (=lane&15), row=kv.
// K/Q LDS swizzle: 16B chunk ^= (row&7). Vt LDS [d][32kv]: chunk ^= ((d>>1)&3).
__global__ __launch_bounds__(256) void k_attn(const short* __restrict__ Qb,
                                              const short* __restrict__ Kb,
                                              const short* __restrict__ Vt,
                                              short* __restrict__ yb) {
  __shared__ short Qs[64 * 128];
  __shared__ short Ks[32 * 128];
  __shared__ short Vs[128 * 32];
  __shared__ short Ps[4][16 * 40];  // per-wave P, padded stride 40 (bank-safe)
  const int tid = threadIdx.x, wid = tid >> 6, lane = tid & 63;
  const int lr = lane & 15, lk = lane >> 4;
  const int bh = blockIdx.y;
  const int q0 = blockIdx.x * 64;
  const size_t baseQK = (size_t)bh * TT * DD;  // same size for V ([D][T])
  const float scale = 0.08838834764831845f;    // 1/sqrt(128)

  // stage Q tile 64x128 (swizzled source chunks)
#pragma unroll
  for (int it = 0; it < 4; ++it) {
    int ch = it * 256 + tid;
    int r = ch >> 4, cc = ch & 15;
    int cs = cc ^ (r & 7);
    lds_load16(Qb + baseQK + (size_t)(q0 + r) * DD + cs * 8,
               Qs + (size_t)(it * 256 + wid * 64) * 8);
  }
  __syncthreads();
  const int qg = q0 + wid * 16 + lr;  // this lane's q (as S^T column)
  s16x8 qf[4];
#pragma unroll
  for (int ds = 0; ds < 4; ++ds) {
    int qrow = wid * 16 + lr;
    int cc = (ds * 4 + lk) ^ (qrow & 7);
    qf[ds] = *(const s16x8*)(Qs + qrow * 128 + cc * 8);
  }

  float mrun = -1e30f, lrun = 0.f;
  f32x4 yacc[8] = {};

  const int nkt = (q0 + 64) / 32;
  for (int kt = 0; kt < nkt; ++kt) {
#pragma unroll
    for (int it = 0; it < 2; ++it) {
      int ch = it * 256 + tid;
      int r = ch >> 4, cc = ch & 15;
      int cs = cc ^ (r & 7);
      lds_load16(Kb + baseQK + (size_t)(kt * 32 + r) * DD + cs * 8,
                 Ks + (size_t)(it * 256 + wid * 64) * 8);
    }
#pragma unroll
    for (int it = 0; it < 2; ++it) {
      int ch = it * 256 + tid;
      int d = ch >> 2, cc = ch & 3;
      int cs = cc ^ ((d >> 1) & 3);
      lds_load16(Vt + baseQK + (size_t)d * TT + kt * 32 + cs * 8,
                 Vs + (size_t)(it * 256 + wid * 64) * 8);
    }
    __syncthreads();

    // S^T = K (A) x Q (B): two 16-kv subtiles
    f32x4 sf[2] = {};
#pragma unroll
    for (int sub = 0; sub < 2; ++sub)
#pragma unroll
      for (int ds = 0; ds < 4; ++ds) {
        int kr = sub * 16 + lr;
        int cc = (ds * 4 + lk) ^ (kr & 7);
        s16x8 kf = *(const s16x8*)(Ks + kr * 128 + cc * 8);
        sf[sub] = __builtin_amdgcn_mfma_f32_16x16x32_bf16(kf, qf[ds], sf[sub], 0, 0, 0);
      }
    // scale + causal mask + tile max (per q = per S^T column)
    float tmax = -1e30f;
#pragma unroll
    for (int sub = 0; sub < 2; ++sub)
#pragma unroll
      for (int r = 0; r < 4; ++r) {
        int kv = kt * 32 + sub * 16 + lk * 4 + r;
        float s = sf[sub][r] * scale;
        s = (kv <= qg) ? s : -1e30f;
        sf[sub][r] = s;
        tmax = fmaxf(tmax, s);
      }
    tmax = fmaxf(tmax, __shfl_xor(tmax, 16, 64));
    tmax = fmaxf(tmax, __shfl_xor(tmax, 32, 64));
    float mnew = fmaxf(mrun, tmax);
    float alpha = __expf(mrun - mnew);
    float psum = 0.f;
#pragma unroll
    for (int sub = 0; sub < 2; ++sub) {
      s16x4 pq;
#pragma unroll
      for (int r = 0; r < 4; ++r) {
        float p = __expf(sf[sub][r] - mnew);
        psum += p;
        pq[r] = bf16_of(p);
      }
      *(s16x4*)(&Ps[wid][lr * 40 + sub * 16 + lk * 4]) = pq;  // P[q][kv] row-major
    }
    psum += __shfl_xor(psum, 16, 64);
    psum += __shfl_xor(psum, 32, 64);
    lrun = lrun * alpha + psum;
    mrun = mnew;
    // rescale yacc (y rows q = lk*4+r -> broadcast alpha from lanes 0..15)
    float ar[4];
#pragma unroll
    for (int r = 0; r < 4; ++r) ar[r] = __shfl(alpha, lk * 4 + r, 64);
#pragma unroll
    for (int f = 0; f < 8; ++f)
#pragma unroll
      for (int r = 0; r < 4; ++r) yacc[f][r] *= ar[r];
    // PV: A=P[q][kv] (one frag, reused for all dn), B=V[kv][d] from Vs[d][kv]
    s16x8 pf = *(const s16x8*)(&Ps[wid][lr * 40 + lk * 8]);
#pragma unroll
    for (int dn = 0; dn < 8; ++dn) {
      int d = dn * 16 + lr;
      int cc = lk ^ ((d >> 1) & 3);
      s16x8 vf = *(const s16x8*)(Vs + d * 32 + cc * 8);
      yacc[dn] = __builtin_amdgcn_mfma_f32_16x16x32_bf16(pf, vf, yacc[dn], 0, 0, 0);
    }
    __syncthreads();
  }
  // epilogue: y[q][d] / l[q] -> yb[B][T][C] bf16
  float linv = 1.f / lrun;
  float lr4[4];
#pragma unroll
  for (int r = 0; r < 4; ++r) lr4[r] = __shfl(linv, lk * 4 + r, 64);
  const int b = bh >> 4, h = bh & 15;
#pragma unroll
  for (int dn = 0; dn < 8; ++dn)
#pragma unroll
    for (int r = 0; r < 4; ++r) {
      int t = q0 + wid * 16 + lk * 4 + r;
      int c = h * DD + dn * 16 + lr;
      yb[((size_t)(b * TT + t)) * CCn + c] = bf16_of(yacc[dn][r] * lr4[r]);
    }
}

extern "C" void kernel_launch(void* const* d_in, const int* in_sizes, int n_in,
                              void* d_out, int out_size, void* d_ws, size_t ws_size,
                              hipStream_t stream) {
  const float* x = (const float*)d_in[0];
  const float* wq = (const float*)d_in[1];
  const float* wk = (const float*)d_in[2];
  const float* wv = (const float*)d_in[3];
  const float* wo = (const float*)d_in[4];
  float* out = (float*)d_out;
  char* ws = (char*)d_ws;

  short* xb = (short*)(ws + 0);                 // 16,777,216
  short* wqT = (short*)(ws + 16777216);         // 8,388,608 each
  short* wkT = (short*)(ws + 25165824);
  short* wvT = (short*)(ws + 33554432);
  short* woT = (short*)(ws + 41943040);
  float* tmp = (float*)(ws + 50331648);         // 33,554,432
  short* Qb = (short*)(ws + 83886080);          // 16,777,216 each
  short* Kb = (short*)(ws + 100663296);
  short* Vt = (short*)(ws + 117440512);
  short* yb = (short*)(ws + 134217728);
  float* cosT = (float*)(ws + 150994944);       // 524,288 each
  float* sinT = (float*)(ws + 151519232);       // end: 152,043,520

  k_tables<<<512, 256, 0, stream>>>(cosT, sinT);
  k_cast_x<<<8192, 256, 0, stream>>>(x, xb);
  k_wtrans<<<dim3(64, 64), 256, 0, stream>>>(wq, wqT);
  k_wtrans<<<dim3(64, 64), 256, 0, stream>>>(wk, wkT);
  k_wtrans<<<dim3(64, 64), 256, 0, stream>>>(wv, wvT);
  k_wtrans<<<dim3(64, 64), 256, 0, stream>>>(wo, woT);

  k_gemm<<<dim3(16, 32), 256, 0, stream>>>(xb, wqT, tmp, MMr, CCn, CCn);
  k_rope<<<16384, 256, 0, stream>>>(tmp, cosT, sinT, Qb);
  k_gemm<<<dim3(16, 32), 256, 0, stream>>>(xb, wkT, tmp, MMr, CCn, CCn);
  k_rope<<<16384, 256, 0, stream>>>(tmp, cosT, sinT, Kb);
  k_gemm<<<dim3(16, 32), 256, 0, stream>>>(xb, wvT, tmp, MMr, CCn, CCn);
  k_vtrans<<<dim3(256, 32), 256, 0, stream>>>(tmp, Vt);

  k_attn<<<dim3(32, 32), 256, 0, stream>>>(Qb, Kb, Vt, yb);
  k_gemm<<<dim3(16, 32), 256, 0, stream>>>(yb, woT, out, MMr, CCn, CCn);
}

// Round 2
// 450.823 us; speedup vs baseline: 1.1812x; 1.1812x over previous
//
#include <hip/hip_runtime.h>
#include <hip/hip_bf16.h>
#include <math.h>

// LlamaStyleAttention: B=2, T=2048, C=2048, H=16, D=128, fp32 in/out.
// Pipeline: cast/transpose -> 3x GEMM(bf16 MFMA) -> RoPE -> flash attn -> GEMM.
// R2: attn rewrite — paired q-tiles (perfect balance), KVBLK=64, K double-buffer,
//     scale folded into K (log2 domain), diag-only mask, defer-max (T13).

#define TT 2048
#define CCn 2048
#define HH 16
#define DD 128
#define BBa 2
#define MMr 4096  // B*T

typedef __attribute__((ext_vector_type(8))) short s16x8;
typedef __attribute__((ext_vector_type(4))) short s16x4;
typedef __attribute__((ext_vector_type(4))) float f32x4;

__device__ __forceinline__ short bf16_of(float f) {
  unsigned u = __float_as_uint(f);
  unsigned r = u + 0x7fffu + ((u >> 16) & 1u);
  return (short)(r >> 16);
}

__device__ __forceinline__ float ex2(float x) {
#if __has_builtin(__builtin_amdgcn_exp2f)
  return __builtin_amdgcn_exp2f(x);
#else
  return exp2f(x);
#endif
}

__device__ __forceinline__ void lds_load16(const void* g, void* l) {
  __builtin_amdgcn_global_load_lds((__attribute__((address_space(1))) void*)g,
                                   (__attribute__((address_space(3))) void*)l,
                                   16, 0, 0);
}

// ---------------- cos/sin tables: [T][64] fp32 ----------------
__global__ __launch_bounds__(256) void k_tables(float* __restrict__ cosT,
                                                float* __restrict__ sinT) {
  int idx = blockIdx.x * 256 + threadIdx.x;  // T*64 = 131072
  int t = idx >> 6, i = idx & 63;
  float inv = powf(10000.0f, -(float)i * (1.0f / 64.0f));
  float f = (float)t * inv;
  cosT[idx] = cosf(f);
  sinT[idx] = sinf(f);
}

// ---------------- x fp32 -> bf16 ----------------
__global__ __launch_bounds__(256) void k_cast_x(const float* __restrict__ x,
                                                short* __restrict__ xb) {
  int i = blockIdx.x * 256 + threadIdx.x;  // n/4 threads
  f32x4 v = ((const f32x4*)x)[i];
  s16x4 o;
#pragma unroll
  for (int j = 0; j < 4; ++j) o[j] = bf16_of(v[j]);
  ((s16x4*)xb)[i] = o;
}

// ---------------- weight transpose+cast: w[K][N] fp32 -> wt[N][K] bf16 ----------------
__global__ __launch_bounds__(256) void k_wtrans(const float* __restrict__ w,
                                                short* __restrict__ wt) {
  __shared__ float tile[32][33];
  int n0 = blockIdx.x * 32, k0 = blockIdx.y * 32;
  int tx = threadIdx.x & 31, ty = threadIdx.x >> 5;  // ty 0..7
#pragma unroll
  for (int j = 0; j < 4; ++j) {
    int k = ty * 4 + j;
    tile[k][tx] = w[(size_t)(k0 + k) * CCn + n0 + tx];
  }
  __syncthreads();
#pragma unroll
  for (int j = 0; j < 4; ++j) {
    int n = ty * 4 + j;
    wt[(size_t)(n0 + n) * CCn + k0 + tx] = bf16_of(tile[tx][n]);
  }
}

// ---------------- V transpose: tmp[B*T][C] fp32 -> Vt[B*H][D][T] bf16 ----------------
__global__ __launch_bounds__(256) void k_vtrans(const float* __restrict__ src,
                                                short* __restrict__ dst) {
  __shared__ float tile[32][33];
  int bh = blockIdx.y, b = bh >> 4, h = bh & 15;
  int dt = blockIdx.x & 3, tt = blockIdx.x >> 2;  // d-tile 0..3, t-tile 0..63
  int tx = threadIdx.x & 31, ty = threadIdx.x >> 5;
  const float* sp = src + ((size_t)(b * TT + tt * 32)) * CCn + h * DD + dt * 32;
#pragma unroll
  for (int j = 0; j < 4; ++j) {
    int tr = ty * 4 + j;
    tile[tr][tx] = sp[(size_t)tr * CCn + tx];  // tile[t_local][d_local]
  }
  __syncthreads();
  short* dp = dst + ((size_t)(bh * DD + dt * 32)) * TT + tt * 32;
#pragma unroll
  for (int j = 0; j < 4; ++j) {
    int dr = ty * 4 + j;
    dp[(size_t)dr * TT + tx] = bf16_of(tile[tx][dr]);
  }
}

// ---------------- RoPE + cast: tmp[B*T][C] fp32 -> dst[B*H][T][D] bf16 ----------------
// mul: 1.0 for Q; scale*log2(e) for K (folds softmax scale + log2 domain into K).
__global__ __launch_bounds__(256) void k_rope(const float* __restrict__ src,
                                              const float* __restrict__ cosT,
                                              const float* __restrict__ sinT,
                                              short* __restrict__ dst, float mul) {
  int idx = blockIdx.x * 256 + threadIdx.x;  // B*T*H*64
  int i = idx & 63;
  int h = (idx >> 6) & 15;
  int t = (idx >> 10) & 2047;
  int b = idx >> 21;
  const float* row = src + ((size_t)(b * TT + t)) * CCn + h * DD;
  float q0 = row[i], q1 = row[i + 64];
  float c = cosT[t * 64 + i], s = sinT[t * 64 + i];
  short* orow = dst + ((size_t)((b * HH + h) * TT + t)) * DD;
  orow[i] = bf16_of((q0 * c - q1 * s) * mul);
  orow[i + 64] = bf16_of((q1 * c + q0 * s) * mul);
}

// ---------------- GEMM: C[M][N] = A[M][K]bf16 x Bt[N][K]bf16, fp32 out ----------------
// m97 structure: 128x128 tile, BK=64, 4 waves (2x2), 4x4 16x16 frags/wave.
#define BKG 64
__global__ __launch_bounds__(256) void k_gemm(const short* __restrict__ A,
                                              const short* __restrict__ Bt,
                                              float* __restrict__ Cc,
                                              int M, int N, int K) {
  __shared__ short As[128 * BKG];
  __shared__ short Bs[128 * BKG];
  const int tid = threadIdx.x, wid = tid >> 6, lane = tid & 63;
  const int wm = wid >> 1, wn = wid & 1;
  const int lr = lane & 15, lk = lane >> 4;
  const int m0 = blockIdx.y * 128, n0 = blockIdx.x * 128;

  f32x4 acc[4][4] = {};
  const int nk = K / BKG;
  for (int kt = 0; kt < nk; ++kt) {
#pragma unroll
    for (int it = 0; it < 4; ++it) {
      int ch = it * 256 + tid;
      int r = ch >> 3, c = (ch & 7) * 8;  // 8 chunks per 64-elem row
      lds_load16(A + (size_t)(m0 + r) * K + kt * BKG + c,
                 As + (size_t)(it * 256 + wid * 64) * 8);
      lds_load16(Bt + (size_t)(n0 + r) * K + kt * BKG + c,
                 Bs + (size_t)(it * 256 + wid * 64) * 8);
    }
    __syncthreads();
#pragma unroll
    for (int ks = 0; ks < 2; ++ks) {
      s16x8 af[4], bf[4];
#pragma unroll
      for (int i = 0; i < 4; ++i) {
        int ar = wm * 64 + i * 16 + lr;
        af[i] = *(const s16x8*)(As + ar * BKG + ks * 32 + lk * 8);
        int br = wn * 64 + i * 16 + lr;
        bf[i] = *(const s16x8*)(Bs + br * BKG + ks * 32 + lk * 8);
      }
#pragma unroll
      for (int i = 0; i < 4; ++i)
#pragma unroll
        for (int j = 0; j < 4; ++j)
          acc[i][j] = __builtin_amdgcn_mfma_f32_16x16x32_bf16(af[i], bf[j],
                                                              acc[i][j], 0, 0, 0);
    }
    __syncthreads();
  }
  // C layout: col=lane&15, row=(lane>>4)*4+reg  [m89-verified]
#pragma unroll
  for (int i = 0; i < 4; ++i)
#pragma unroll
    for (int j = 0; j < 4; ++j) {
      int col = n0 + wn * 64 + j * 16 + lr;
      int rb = m0 + wm * 64 + i * 16 + lk * 4;
#pragma unroll
      for (int r = 0; r < 4; ++r)
        Cc[(size_t)(rb + r) * N + col] = acc[i][j][r];
    }
}

// ---------------- Flash attention (R2) ----------------
// grid (16, B*H). Block bx processes q-tiles {bx, 31-bx} (64 rows each) ->
// constant 33 kv-tiles of work per block. 4 waves; wave w owns 16 q rows.
// Swapped QK^T: mfma(K,Q) -> S^T col=q(lane&15), row=kv. K pre-scaled by
// scale*log2e so softmax runs in exp2 domain with no per-element scaling.
// K LDS [64][128] double-buffered, chunk-swizzled (^row&7). V LDS [128][64]
// single-buffered, chunk-swizzled (^d&7). Causal mask only on diagonal tile.
__global__ __launch_bounds__(256) void k_attn(const short* __restrict__ Qb,
                                              const short* __restrict__ Kb,
                                              const short* __restrict__ Vt,
                                              short* __restrict__ yb) {
  __shared__ short Ks[2][64 * 128];  // 16 KB each
  __shared__ short Vs[128 * 64];     // 16 KB
  __shared__ short Ps[4][16 * 72];   // per-wave P rows, stride 72 (9 KB)
  const int tid = threadIdx.x, wid = tid >> 6, lane = tid & 63;
  const int lr = lane & 15, lk = lane >> 4;
  const int bh = blockIdx.y, bx = blockIdx.x;
  const size_t baseQK = (size_t)bh * TT * DD;
  const int b = bh >> 4, h = bh & 15;

  auto stageK = [&](int bi, int kt2) {
#pragma unroll
    for (int it = 0; it < 4; ++it) {
      int ch = it * 256 + tid;
      int r = ch >> 4, cc = ch & 15;
      int cs = cc ^ (r & 7);
      lds_load16(Kb + baseQK + (size_t)(kt2 * 64 + r) * DD + cs * 8,
                 &Ks[bi][(size_t)(it * 256 + wid * 64) * 8]);
    }
  };
  auto stageV = [&](int kt2) {
#pragma unroll
    for (int it = 0; it < 4; ++it) {
      int ch = it * 256 + tid;
      int d = ch >> 3, kc = ch & 7;
      int cs = kc ^ (d & 7);
      lds_load16(Vt + baseQK + (size_t)d * TT + kt2 * 64 + cs * 8,
                 &Vs[(size_t)(it * 256 + wid * 64) * 8]);
    }
  };

#pragma unroll 1
  for (int pass = 0; pass < 2; ++pass) {
    const int qt = pass ? (31 - bx) : bx;
    const int q0 = qt * 64;
    const int qg = q0 + wid * 16 + lr;  // this lane's q row
    // Q fragments straight from global (once per pass)
    s16x8 qf[4];
#pragma unroll
    for (int ds = 0; ds < 4; ++ds)
      qf[ds] = *(const s16x8*)(Qb + baseQK + (size_t)qg * DD + (ds * 4 + lk) * 8);

    float mrun = -3.0e38f, lrun = 0.f;
    f32x4 yacc[8] = {};

    const int nkt = qt + 1;
    stageK(0, 0);
    stageV(0);
    __syncthreads();
    int buf = 0;
#pragma unroll 1
    for (int kt = 0; kt < nkt; ++kt) {
      if (kt + 1 < nkt) stageK(buf ^ 1, kt + 1);
      // ---- QK^T: S^T[64kv][16q] ----
      f32x4 sf[4] = {};
#pragma unroll
      for (int sub = 0; sub < 4; ++sub) {
        int kr = sub * 16 + lr;
#pragma unroll
        for (int ds = 0; ds < 4; ++ds) {
          int cc = (ds * 4 + lk) ^ (kr & 7);
          s16x8 kf = *(const s16x8*)(&Ks[buf][kr * 128 + cc * 8]);
          sf[sub] = __builtin_amdgcn_mfma_f32_16x16x32_bf16(kf, qf[ds], sf[sub], 0, 0, 0);
        }
      }
      const int kvbase = kt * 64;
      // causal mask: only the diagonal tile needs it (wave-uniform test)
      if (kvbase + 63 > q0 + wid * 16) {
#pragma unroll
        for (int sub = 0; sub < 4; ++sub)
#pragma unroll
          for (int r = 0; r < 4; ++r) {
            int kv = kvbase + sub * 16 + lk * 4 + r;
            if (kv > qg) sf[sub][r] = -3.0e38f;
          }
      }
      float tmax = -3.0e38f;
#pragma unroll
      for (int sub = 0; sub < 4; ++sub)
#pragma unroll
        for (int r = 0; r < 4; ++r) tmax = fmaxf(tmax, sf[sub][r]);
      tmax = fmaxf(tmax, __shfl_xor(tmax, 16, 64));
      tmax = fmaxf(tmax, __shfl_xor(tmax, 32, 64));
      // defer-max (T13): rescale only when tile max pushes past mrun+11 (log2)
      if (!__all(tmax <= mrun + 11.0f)) {
        float mnew = fmaxf(mrun, tmax);
        float alpha = ex2(mrun - mnew);
        mrun = mnew;
        lrun *= alpha;
        float ar[4];
#pragma unroll
        for (int r = 0; r < 4; ++r) ar[r] = __shfl(alpha, lk * 4 + r, 64);
#pragma unroll
        for (int dn = 0; dn < 8; ++dn)
#pragma unroll
          for (int r = 0; r < 4; ++r) yacc[dn][r] *= ar[r];
      }
      float psum = 0.f;
#pragma unroll
      for (int sub = 0; sub < 4; ++sub) {
        s16x4 pq;
#pragma unroll
        for (int r = 0; r < 4; ++r) {
          float p = ex2(sf[sub][r] - mrun);
          psum += p;
          pq[r] = bf16_of(p);
        }
        *(s16x4*)(&Ps[wid][lr * 72 + sub * 16 + lk * 4]) = pq;
      }
      psum += __shfl_xor(psum, 16, 64);
      psum += __shfl_xor(psum, 32, 64);
      lrun += psum;
      __syncthreads();  // drains V(kt) (and K prefetch); Ps visible to self
      // ---- PV: y[16q][128d] += P[16q][64kv] x V[64kv][128d] ----
      s16x8 pf0 = *(const s16x8*)(&Ps[wid][lr * 72 + lk * 8]);
      s16x8 pf1 = *(const s16x8*)(&Ps[wid][lr * 72 + 32 + lk * 8]);
#pragma unroll
      for (int dn = 0; dn < 8; ++dn) {
        int d = dn * 16 + lr;
        s16x8 vf0 = *(const s16x8*)(&Vs[d * 64 + (lk ^ (d & 7)) * 8]);
        yacc[dn] = __builtin_amdgcn_mfma_f32_16x16x32_bf16(pf0, vf0, yacc[dn], 0, 0, 0);
        s16x8 vf1 = *(const s16x8*)(&Vs[d * 64 + ((4 + lk) ^ (d & 7)) * 8]);
        yacc[dn] = __builtin_amdgcn_mfma_f32_16x16x32_bf16(pf1, vf1, yacc[dn], 0, 0, 0);
      }
      __syncthreads();  // all waves done with Vs & Ks[buf]
      if (kt + 1 < nkt) stageV(kt + 1);
      buf ^= 1;
    }
    // epilogue: y[q][d] / l[q] -> yb[B][T][C] bf16
    float linv = 1.f / lrun;
    float lr4[4];
#pragma unroll
    for (int r = 0; r < 4; ++r) lr4[r] = __shfl(linv, lk * 4 + r, 64);
#pragma unroll
    for (int dn = 0; dn < 8; ++dn)
#pragma unroll
      for (int r = 0; r < 4; ++r) {
        int t = q0 + wid * 16 + lk * 4 + r;
        int c = h * DD + dn * 16 + lr;
        yb[((size_t)(b * TT + t)) * CCn + c] = bf16_of(yacc[dn][r] * lr4[r]);
      }
  }
}

extern "C" void kernel_launch(void* const* d_in, const int* in_sizes, int n_in,
                              void* d_out, int out_size, void* d_ws, size_t ws_size,
                              hipStream_t stream) {
  const float* x = (const float*)d_in[0];
  const float* wq = (const float*)d_in[1];
  const float* wk = (const float*)d_in[2];
  const float* wv = (const float*)d_in[3];
  const float* wo = (const float*)d_in[4];
  float* out = (float*)d_out;
  char* ws = (char*)d_ws;

  short* xb = (short*)(ws + 0);                 // 16,777,216
  short* wqT = (short*)(ws + 16777216);         // 8,388,608 each
  short* wkT = (short*)(ws + 25165824);
  short* wvT = (short*)(ws + 33554432);
  short* woT = (short*)(ws + 41943040);
  float* tmp = (float*)(ws + 50331648);         // 33,554,432
  short* Qb = (short*)(ws + 83886080);          // 16,777,216 each
  short* Kb = (short*)(ws + 100663296);
  short* Vt = (short*)(ws + 117440512);
  short* yb = (short*)(ws + 134217728);
  float* cosT = (float*)(ws + 150994944);       // 524,288 each
  float* sinT = (float*)(ws + 151519232);       // end: 152,043,520

  const float kmul = 1.4426950408889634f / sqrtf(128.0f);  // log2e * 1/sqrt(D)

  k_tables<<<512, 256, 0, stream>>>(cosT, sinT);
  k_cast_x<<<8192, 256, 0, stream>>>(x, xb);
  k_wtrans<<<dim3(64, 64), 256, 0, stream>>>(wq, wqT);
  k_wtrans<<<dim3(64, 64), 256, 0, stream>>>(wk, wkT);
  k_wtrans<<<dim3(64, 64), 256, 0, stream>>>(wv, wvT);
  k_wtrans<<<dim3(64, 64), 256, 0, stream>>>(wo, woT);

  k_gemm<<<dim3(16, 32), 256, 0, stream>>>(xb, wqT, tmp, MMr, CCn, CCn);
  k_rope<<<16384, 256, 0, stream>>>(tmp, cosT, sinT, Qb, 1.0f);
  k_gemm<<<dim3(16, 32), 256, 0, stream>>>(xb, wkT, tmp, MMr, CCn, CCn);
  k_rope<<<16384, 256, 0, stream>>>(tmp, cosT, sinT, Kb, kmul);
  k_gemm<<<dim3(16, 32), 256, 0, stream>>>(xb, wvT, tmp, MMr, CCn, CCn);
  k_vtrans<<<dim3(256, 32), 256, 0, stream>>>(tmp, Vt);

  k_attn<<<dim3(16, 32), 256, 0, stream>>>(Qb, Kb, Vt, yb);
  k_gemm<<<dim3(16, 32), 256, 0, stream>>>(yb, woT, out, MMr, CCn, CCn);
}

// Round 3
// 425.885 us; speedup vs baseline: 1.2504x; 1.0586x over previous
//
#include <hip/hip_runtime.h>
#include <hip/hip_bf16.h>
#include <math.h>

// LlamaStyleAttention: B=2, T=2048, C=2048, H=16, D=128, fp32 in/out.
// R3: fused QKV GEMM (N=6144) + 256^2 8-phase MFMA GEMM template
//     (T2 swizzle + T3/T4 counted-vmcnt pipeline + T5 setprio).
//     GEMM outputs bf16 directly; rope vectorized; attn unchanged from R2.

#define TT 2048
#define CCn 2048
#define HH 16
#define DD 128
#define MMr 4096   // B*T
#define NQKV 6144  // 3*C

typedef __attribute__((ext_vector_type(8))) short s16x8;
typedef __attribute__((ext_vector_type(4))) short s16x4;
typedef __attribute__((ext_vector_type(4))) float f32x4;

__device__ __forceinline__ short bf16_of(float f) {
  unsigned u = __float_as_uint(f);
  unsigned r = u + 0x7fffu + ((u >> 16) & 1u);
  return (short)(r >> 16);
}
__device__ __forceinline__ float f_of_bf16(short s) {
  return __uint_as_float(((unsigned)(unsigned short)s) << 16);
}
__device__ __forceinline__ float ex2(float x) { return exp2f(x); }

__device__ __forceinline__ void lds_load16(const void* g, void* l) {
  __builtin_amdgcn_global_load_lds((__attribute__((address_space(1))) void*)g,
                                   (__attribute__((address_space(3))) void*)l,
                                   16, 0, 0);
}

// ---------------- cos/sin tables: [T][64] fp32 ----------------
__global__ __launch_bounds__(256) void k_tables(float* __restrict__ cosT,
                                                float* __restrict__ sinT) {
  int idx = blockIdx.x * 256 + threadIdx.x;
  int t = idx >> 6, i = idx & 63;
  float inv = powf(10000.0f, -(float)i * (1.0f / 64.0f));
  float f = (float)t * inv;
  cosT[idx] = cosf(f);
  sinT[idx] = sinf(f);
}

// ---------------- x fp32 -> bf16 ----------------
__global__ __launch_bounds__(256) void k_cast_x(const float* __restrict__ x,
                                                short* __restrict__ xb) {
  int i = blockIdx.x * 256 + threadIdx.x;
  f32x4 v = ((const f32x4*)x)[i];
  s16x4 o;
#pragma unroll
  for (int j = 0; j < 4; ++j) o[j] = bf16_of(v[j]);
  ((s16x4*)xb)[i] = o;
}

// ---------------- weight transpose+cast: w[K][N] fp32 -> wt[N][K] bf16 ----------------
__global__ __launch_bounds__(256) void k_wtrans(const float* __restrict__ w,
                                                short* __restrict__ wt) {
  __shared__ float tile[32][33];
  int n0 = blockIdx.x * 32, k0 = blockIdx.y * 32;
  int tx = threadIdx.x & 31, ty = threadIdx.x >> 5;
#pragma unroll
  for (int j = 0; j < 4; ++j) {
    int k = ty * 4 + j;
    tile[k][tx] = w[(size_t)(k0 + k) * CCn + n0 + tx];
  }
  __syncthreads();
#pragma unroll
  for (int j = 0; j < 4; ++j) {
    int n = ty * 4 + j;
    wt[(size_t)(n0 + n) * CCn + k0 + tx] = bf16_of(tile[tx][n]);
  }
}

// ---------------- V transpose: qkv[B*T][6144] bf16 (V at col 4096) -> Vt[B*H][D][T] ----
__global__ __launch_bounds__(256) void k_vtrans(const short* __restrict__ src,
                                                short* __restrict__ dst) {
  __shared__ short tile[32][33];
  int bh = blockIdx.y, b = bh >> 4, h = bh & 15;
  int dt = blockIdx.x & 3, tt = blockIdx.x >> 2;
  int tx = threadIdx.x & 31, ty = threadIdx.x >> 5;
  const short* sp = src + ((size_t)(b * TT + tt * 32)) * NQKV + 4096 + h * DD + dt * 32;
#pragma unroll
  for (int j = 0; j < 4; ++j) {
    int tr = ty * 4 + j;
    tile[tr][tx] = sp[(size_t)tr * NQKV + tx];
  }
  __syncthreads();
  short* dp = dst + ((size_t)(bh * DD + dt * 32)) * TT + tt * 32;
#pragma unroll
  for (int j = 0; j < 4; ++j) {
    int dr = ty * 4 + j;
    dp[(size_t)dr * TT + tx] = tile[tx][dr];
  }
}

// ---------------- RoPE: qkv bf16 (col off) -> dst[B*H][T][D] bf16, vectorized x4 ------
__global__ __launch_bounds__(256) void k_rope(const short* __restrict__ qkv, int coff,
                                              const float* __restrict__ cosT,
                                              const float* __restrict__ sinT,
                                              short* __restrict__ dst, float mul) {
  int idx = blockIdx.x * 256 + threadIdx.x;  // B*T*H*16 = 1,048,576
  int i4 = (idx & 15) * 4;
  int h = (idx >> 4) & 15;
  int t = (idx >> 8) & 2047;
  int b = idx >> 19;
  const short* row = qkv + ((size_t)(b * TT + t)) * NQKV + coff + h * DD;
  s16x4 v0 = *(const s16x4*)(row + i4);
  s16x4 v1 = *(const s16x4*)(row + i4 + 64);
  f32x4 c4 = *(const f32x4*)(cosT + t * 64 + i4);
  f32x4 s4 = *(const f32x4*)(sinT + t * 64 + i4);
  s16x4 o0, o1;
#pragma unroll
  for (int j = 0; j < 4; ++j) {
    float a = f_of_bf16(v0[j]), bb = f_of_bf16(v1[j]);
    o0[j] = bf16_of((a * c4[j] - bb * s4[j]) * mul);
    o1[j] = bf16_of((bb * c4[j] + a * s4[j]) * mul);
  }
  short* orow = dst + ((size_t)((b * HH + h) * TT + t)) * DD;
  *(s16x4*)(orow + i4) = o0;
  *(s16x4*)(orow + i4 + 64) = o1;
}

// ---------------- 256^2 8-phase GEMM: C[M][N] = A[M][K] x Bt[N][K], bf16 in ----------
// 512 thr = 8 waves (2M x 4N); per-wave 128x64 out; BK=64 split in two K-halves [256][32].
// LDS: A 4 slots (2 dbuf x 2 khalf) 16KB + B same = 128KB. Chunk swizzle cs=cc^((r>>1)&3)
// applied on stage SOURCE (linear LDS dest, rule 21) and on fragment reads.
// Per K-tile: 4 phases {ds_read frags, stage 1 half-tile(2x gload_lds16), barrier,
// setprio(1), 16 MFMA, setprio(0), barrier}; counted vmcnt(4) once per K-tile.
// Stage schedule: ph0: kt+1 A-h1 | ph1: kt+1 B-h1 | ph2: kt+2 A-h0 | ph3: kt+2 B-h0.
// Lifetimes: h0 slots last read ph1, freed by ph1's closing barrier -> kt+2 h0 safe;
// boundary vmcnt(4) leaves only kt+2-h0 (4 loads) in flight -> kt+1 fully landed.
template <bool BF16OUT>
__global__ __launch_bounds__(512, 2) void k_gemm256(const short* __restrict__ A,
                                                    const short* __restrict__ Bt,
                                                    void* __restrict__ Cout,
                                                    int M, int N, int K) {
  __shared__ short smem[65536];  // 128 KiB
  const int tid = threadIdx.x, wid = tid >> 6, lane = tid & 63;
  const int wm = wid >> 2, wn = wid & 3;  // 2 x 4 waves
  const int lr = lane & 15, lk = lane >> 4;
  const int swz = (lk ^ ((lr >> 1) & 3)) * 8;

  // bijective XCD swizzle (m204)
  int nwg = gridDim.x, orig = blockIdx.x;
  int xcd = orig & 7, idx = orig >> 3;
  int q = nwg >> 3, rmd = nwg & 7;
  int wg = (xcd < rmd) ? (xcd * (q + 1) + idx)
                       : (rmd * (q + 1) + (xcd - rmd) * q + idx);
  const int NBM = M >> 8;
  const int m0 = (wg % NBM) * 256, n0 = (wg / NBM) * 256;

  const int ldsbase = (tid & ~63);  // wave-uniform LDS part; HW adds lane*16B

  auto stageHalf = [&](const short* src, int r0, int slot, int kt, int h) {
#pragma unroll
    for (int l = 0; l < 2; ++l) {
      int lin = l * 512 + tid;
      int rr = lin >> 2, cs = lin & 3;
      int cc = cs ^ ((rr >> 1) & 3);
      lds_load16(src + (size_t)(r0 + rr) * K + kt * 64 + h * 32 + cc * 8,
                 smem + slot + (l * 512 + ldsbase) * 8);
    }
  };
  // slot offsets (shorts): A: buf*16384 + h*8192 ; B: 32768 + same
  f32x4 acc[8][4] = {};
  s16x8 af[4], bfr[4];

  const int nk = K >> 6;
  // ---- prologue: K0 all 4 half-tiles + K1 h0 pair ----
  stageHalf(A, m0, 0, 0, 0);
  stageHalf(Bt, n0, 32768, 0, 0);
  stageHalf(A, m0, 8192, 0, 1);
  stageHalf(Bt, n0, 32768 + 8192, 0, 1);
  stageHalf(A, m0, 16384, 1, 0);
  stageHalf(Bt, n0, 32768 + 16384, 1, 0);
  asm volatile("s_waitcnt vmcnt(4)" ::: "memory");
  __builtin_amdgcn_s_barrier();

#define PHASE_MFMA(mh)                                                        \
  __builtin_amdgcn_s_setprio(1);                                              \
  _Pragma("unroll") for (int i = 0; i < 4; ++i)                               \
      _Pragma("unroll") for (int j = 0; j < 4; ++j)                           \
      acc[(mh)*4 + i][j] = __builtin_amdgcn_mfma_f32_16x16x32_bf16(           \
          af[i], bfr[j], acc[(mh)*4 + i][j], 0, 0, 0);                        \
  __builtin_amdgcn_s_setprio(0);

#define LOAD_A(mh, ks, abuf)                                                  \
  _Pragma("unroll") for (int i = 0; i < 4; ++i)                               \
      af[i] = *(const s16x8*)(smem + (abuf)*16384 + (ks)*8192 +               \
                              (wm * 128 + (mh)*64 + i * 16 + lr) * 32 + swz);
#define LOAD_B(ks, abuf)                                                      \
  _Pragma("unroll") for (int j = 0; j < 4; ++j)                               \
      bfr[j] = *(const s16x8*)(smem + 32768 + (abuf)*16384 + (ks)*8192 +      \
                               (wn * 64 + j * 16 + lr) * 32 + swz);

#pragma unroll 1
  for (int kt = 0; kt < nk; ++kt) {
    const int buf = kt & 1, nbuf = buf ^ 1;
    const bool s1 = (kt + 1 < nk), s2 = (kt + 2 < nk);
    // ph0 (mh0, ks0)
    LOAD_B(0, buf);
    LOAD_A(0, 0, buf);
    if (s1) stageHalf(A, m0, nbuf * 16384 + 8192, kt + 1, 1);
    __builtin_amdgcn_s_barrier();
    PHASE_MFMA(0);
    __builtin_amdgcn_s_barrier();
    // ph1 (mh1, ks0)
    LOAD_A(1, 0, buf);
    if (s1) stageHalf(Bt, n0, 32768 + nbuf * 16384 + 8192, kt + 1, 1);
    __builtin_amdgcn_s_barrier();
    PHASE_MFMA(1);
    __builtin_amdgcn_s_barrier();
    // ph2 (mh0, ks1)
    LOAD_B(1, buf);
    LOAD_A(0, 1, buf);
    if (s2) stageHalf(A, m0, buf * 16384, kt + 2, 0);
    __builtin_amdgcn_s_barrier();
    PHASE_MFMA(0);
    __builtin_amdgcn_s_barrier();
    // ph3 (mh1, ks1)
    LOAD_A(1, 1, buf);
    if (s2) stageHalf(Bt, n0, 32768 + buf * 16384, kt + 2, 0);
    __builtin_amdgcn_s_barrier();
    PHASE_MFMA(1);
    asm volatile("s_waitcnt vmcnt(4)" ::: "memory");
    __builtin_amdgcn_s_barrier();
  }
#undef PHASE_MFMA
#undef LOAD_A
#undef LOAD_B

  // epilogue: C layout col=lr, row=lk*4+rr per frag
#pragma unroll
  for (int fi = 0; fi < 8; ++fi)
#pragma unroll
    for (int j = 0; j < 4; ++j) {
      int row = m0 + wm * 128 + (fi >> 2) * 64 + (fi & 3) * 16 + lk * 4;
      int col = n0 + wn * 64 + j * 16 + lr;
#pragma unroll
      for (int rr = 0; rr < 4; ++rr) {
        if (BF16OUT)
          ((short*)Cout)[(size_t)(row + rr) * N + col] = bf16_of(acc[fi][j][rr]);
        else
          ((float*)Cout)[(size_t)(row + rr) * N + col] = acc[fi][j][rr];
      }
    }
}

// ---------------- Flash attention (unchanged from R2) ----------------
__global__ __launch_bounds__(256) void k_attn(const short* __restrict__ Qb,
                                              const short* __restrict__ Kb,
                                              const short* __restrict__ Vt,
                                              short* __restrict__ yb) {
  __shared__ short Ks[2][64 * 128];
  __shared__ short Vs[128 * 64];
  __shared__ short Ps[4][16 * 72];
  const int tid = threadIdx.x, wid = tid >> 6, lane = tid & 63;
  const int lr = lane & 15, lk = lane >> 4;
  const int bh = blockIdx.y, bx = blockIdx.x;
  const size_t baseQK = (size_t)bh * TT * DD;
  const int b = bh >> 4, h = bh & 15;

  auto stageK = [&](int bi, int kt2) {
#pragma unroll
    for (int it = 0; it < 4; ++it) {
      int ch = it * 256 + tid;
      int r = ch >> 4, cc = ch & 15;
      int cs = cc ^ (r & 7);
      lds_load16(Kb + baseQK + (size_t)(kt2 * 64 + r) * DD + cs * 8,
                 &Ks[bi][(size_t)(it * 256 + wid * 64) * 8]);
    }
  };
  auto stageV = [&](int kt2) {
#pragma unroll
    for (int it = 0; it < 4; ++it) {
      int ch = it * 256 + tid;
      int d = ch >> 3, kc = ch & 7;
      int cs = kc ^ (d & 7);
      lds_load16(Vt + baseQK + (size_t)d * TT + kt2 * 64 + cs * 8,
                 &Vs[(size_t)(it * 256 + wid * 64) * 8]);
    }
  };

#pragma unroll 1
  for (int pass = 0; pass < 2; ++pass) {
    const int qt = pass ? (31 - bx) : bx;
    const int q0 = qt * 64;
    const int qg = q0 + wid * 16 + lr;
    s16x8 qf[4];
#pragma unroll
    for (int ds = 0; ds < 4; ++ds)
      qf[ds] = *(const s16x8*)(Qb + baseQK + (size_t)qg * DD + (ds * 4 + lk) * 8);

    float mrun = -3.0e38f, lrun = 0.f;
    f32x4 yacc[8] = {};

    const int nkt = qt + 1;
    stageK(0, 0);
    stageV(0);
    __syncthreads();
    int buf = 0;
#pragma unroll 1
    for (int kt = 0; kt < nkt; ++kt) {
      if (kt + 1 < nkt) stageK(buf ^ 1, kt + 1);
      f32x4 sf[4] = {};
#pragma unroll
      for (int sub = 0; sub < 4; ++sub) {
        int kr = sub * 16 + lr;
#pragma unroll
        for (int ds = 0; ds < 4; ++ds) {
          int cc = (ds * 4 + lk) ^ (kr & 7);
          s16x8 kf = *(const s16x8*)(&Ks[buf][kr * 128 + cc * 8]);
          sf[sub] = __builtin_amdgcn_mfma_f32_16x16x32_bf16(kf, qf[ds], sf[sub], 0, 0, 0);
        }
      }
      const int kvbase = kt * 64;
      if (kvbase + 63 > q0 + wid * 16) {
#pragma unroll
        for (int sub = 0; sub < 4; ++sub)
#pragma unroll
          for (int r = 0; r < 4; ++r) {
            int kv = kvbase + sub * 16 + lk * 4 + r;
            if (kv > qg) sf[sub][r] = -3.0e38f;
          }
      }
      float tmax = -3.0e38f;
#pragma unroll
      for (int sub = 0; sub < 4; ++sub)
#pragma unroll
        for (int r = 0; r < 4; ++r) tmax = fmaxf(tmax, sf[sub][r]);
      tmax = fmaxf(tmax, __shfl_xor(tmax, 16, 64));
      tmax = fmaxf(tmax, __shfl_xor(tmax, 32, 64));
      if (!__all(tmax <= mrun + 11.0f)) {
        float mnew = fmaxf(mrun, tmax);
        float alpha = ex2(mrun - mnew);
        mrun = mnew;
        lrun *= alpha;
        float ar[4];
#pragma unroll
        for (int r = 0; r < 4; ++r) ar[r] = __shfl(alpha, lk * 4 + r, 64);
#pragma unroll
        for (int dn = 0; dn < 8; ++dn)
#pragma unroll
          for (int r = 0; r < 4; ++r) yacc[dn][r] *= ar[r];
      }
      float psum = 0.f;
#pragma unroll
      for (int sub = 0; sub < 4; ++sub) {
        s16x4 pq;
#pragma unroll
        for (int r = 0; r < 4; ++r) {
          float p = ex2(sf[sub][r] - mrun);
          psum += p;
          pq[r] = bf16_of(p);
        }
        *(s16x4*)(&Ps[wid][lr * 72 + sub * 16 + lk * 4]) = pq;
      }
      psum += __shfl_xor(psum, 16, 64);
      psum += __shfl_xor(psum, 32, 64);
      lrun += psum;
      __syncthreads();
      s16x8 pf0 = *(const s16x8*)(&Ps[wid][lr * 72 + lk * 8]);
      s16x8 pf1 = *(const s16x8*)(&Ps[wid][lr * 72 + 32 + lk * 8]);
#pragma unroll
      for (int dn = 0; dn < 8; ++dn) {
        int d = dn * 16 + lr;
        s16x8 vf0 = *(const s16x8*)(&Vs[d * 64 + (lk ^ (d & 7)) * 8]);
        yacc[dn] = __builtin_amdgcn_mfma_f32_16x16x32_bf16(pf0, vf0, yacc[dn], 0, 0, 0);
        s16x8 vf1 = *(const s16x8*)(&Vs[d * 64 + ((4 + lk) ^ (d & 7)) * 8]);
        yacc[dn] = __builtin_amdgcn_mfma_f32_16x16x32_bf16(pf1, vf1, yacc[dn], 0, 0, 0);
      }
      __syncthreads();
      if (kt + 1 < nkt) stageV(kt + 1);
      buf ^= 1;
    }
    float linv = 1.f / lrun;
    float lr4[4];
#pragma unroll
    for (int r = 0; r < 4; ++r) lr4[r] = __shfl(linv, lk * 4 + r, 64);
#pragma unroll
    for (int dn = 0; dn < 8; ++dn)
#pragma unroll
      for (int r = 0; r < 4; ++r) {
        int t = q0 + wid * 16 + lk * 4 + r;
        int c = h * DD + dn * 16 + lr;
        yb[((size_t)(b * TT + t)) * CCn + c] = bf16_of(yacc[dn][r] * lr4[r]);
      }
  }
}

extern "C" void kernel_launch(void* const* d_in, const int* in_sizes, int n_in,
                              void* d_out, int out_size, void* d_ws, size_t ws_size,
                              hipStream_t stream) {
  const float* x = (const float*)d_in[0];
  const float* wq = (const float*)d_in[1];
  const float* wk = (const float*)d_in[2];
  const float* wv = (const float*)d_in[3];
  const float* wo = (const float*)d_in[4];
  float* out = (float*)d_out;
  char* ws = (char*)d_ws;

  short* xb = (short*)(ws + 0);                 // 16,777,216
  short* wqkvT = (short*)(ws + 16777216);       // [6144][2048] bf16 = 25,165,824
  short* woT = (short*)(ws + 41943040);         // 8,388,608
  short* qkv = (short*)(ws + 50331648);         // [4096][6144] bf16 = 50,331,648
  short* yb = (short*)(ws + 50331648);          // alias: reused after qkv consumed
  short* Qb = (short*)(ws + 100663296);         // 16,777,216 each
  short* Kb = (short*)(ws + 117440512);
  short* Vt = (short*)(ws + 134217728);
  float* cosT = (float*)(ws + 150994944);       // 524,288 each
  float* sinT = (float*)(ws + 151519232);       // end: 152,043,520

  const float kmul = 1.4426950408889634f / sqrtf(128.0f);  // log2e / sqrt(D)

  k_tables<<<512, 256, 0, stream>>>(cosT, sinT);
  k_cast_x<<<8192, 256, 0, stream>>>(x, xb);
  k_wtrans<<<dim3(64, 64), 256, 0, stream>>>(wq, wqkvT);
  k_wtrans<<<dim3(64, 64), 256, 0, stream>>>(wk, wqkvT + (size_t)2048 * 2048);
  k_wtrans<<<dim3(64, 64), 256, 0, stream>>>(wv, wqkvT + (size_t)4096 * 2048);
  k_wtrans<<<dim3(64, 64), 256, 0, stream>>>(wo, woT);

  // fused QKV GEMM: [4096][2048] x [6144][2048]^T -> bf16 [4096][6144]
  k_gemm256<true><<<16 * 24, 512, 0, stream>>>(xb, wqkvT, qkv, MMr, NQKV, CCn);

  k_rope<<<4096, 256, 0, stream>>>(qkv, 0, cosT, sinT, Qb, 1.0f);
  k_rope<<<4096, 256, 0, stream>>>(qkv, 2048, cosT, sinT, Kb, kmul);
  k_vtrans<<<dim3(256, 32), 256, 0, stream>>>(qkv, Vt);

  k_attn<<<dim3(16, 32), 256, 0, stream>>>(Qb, Kb, Vt, yb);

  // output GEMM: [4096][2048] x [2048][2048]^T -> fp32 out
  k_gemm256<false><<<16 * 8, 512, 0, stream>>>(yb, woT, out, MMr, CCn, CCn);
}

// Round 4
// 401.400 us; speedup vs baseline: 1.3267x; 1.0610x over previous
//
#include <hip/hip_runtime.h>
#include <hip/hip_bf16.h>
#include <math.h>

// LlamaStyleAttention: B=2, T=2048, C=2048, H=16, D=128, fp32 in/out.
// R4: grid-perfect GEMM tiles — QKV 128x384 (grid 512 = 2 rounds),
//     wo 128x256 (grid 256 = 1 round); unified 4-phase counted-vmcnt template.
//     Aux merged: 1 wtrans launch (4 weights), 1 rope launch (Q+K).

#define TT 2048
#define CCn 2048
#define HH 16
#define DD 128
#define MMr 4096   // B*T
#define NQKV 6144  // 3*C

typedef __attribute__((ext_vector_type(8))) short s16x8;
typedef __attribute__((ext_vector_type(4))) short s16x4;
typedef __attribute__((ext_vector_type(4))) float f32x4;

__device__ __forceinline__ short bf16_of(float f) {
  unsigned u = __float_as_uint(f);
  unsigned r = u + 0x7fffu + ((u >> 16) & 1u);
  return (short)(r >> 16);
}
__device__ __forceinline__ float f_of_bf16(short s) {
  return __uint_as_float(((unsigned)(unsigned short)s) << 16);
}
__device__ __forceinline__ float ex2(float x) { return exp2f(x); }

__device__ __forceinline__ void lds_load16(const void* g, void* l) {
  __builtin_amdgcn_global_load_lds((__attribute__((address_space(1))) void*)g,
                                   (__attribute__((address_space(3))) void*)l,
                                   16, 0, 0);
}

// ---------------- cos/sin tables: [T][64] fp32 ----------------
__global__ __launch_bounds__(256) void k_tables(float* __restrict__ cosT,
                                                float* __restrict__ sinT) {
  int idx = blockIdx.x * 256 + threadIdx.x;
  int t = idx >> 6, i = idx & 63;
  float inv = powf(10000.0f, -(float)i * (1.0f / 64.0f));
  float f = (float)t * inv;
  cosT[idx] = cosf(f);
  sinT[idx] = sinf(f);
}

// ---------------- x fp32 -> bf16 ----------------
__global__ __launch_bounds__(256) void k_cast_x(const float* __restrict__ x,
                                                short* __restrict__ xb) {
  int i = blockIdx.x * 256 + threadIdx.x;
  f32x4 v = ((const f32x4*)x)[i];
  s16x4 o;
#pragma unroll
  for (int j = 0; j < 4; ++j) o[j] = bf16_of(v[j]);
  ((s16x4*)xb)[i] = o;
}

// ------------- weight transpose+cast (all 4 weights, z-indexed) -------------
__global__ __launch_bounds__(256) void k_wtrans4(const float* __restrict__ w0,
                                                 const float* __restrict__ w1,
                                                 const float* __restrict__ w2,
                                                 const float* __restrict__ w3,
                                                 short* __restrict__ wqkvT,
                                                 short* __restrict__ woT) {
  __shared__ float tile[32][33];
  int z = blockIdx.z;
  const float* w = (z == 0) ? w0 : (z == 1) ? w1 : (z == 2) ? w2 : w3;
  short* wt = (z == 3) ? woT : wqkvT + (size_t)z * 2048 * 2048;
  int n0 = blockIdx.x * 32, k0 = blockIdx.y * 32;
  int tx = threadIdx.x & 31, ty = threadIdx.x >> 5;
#pragma unroll
  for (int j = 0; j < 4; ++j) {
    int k = ty * 4 + j;
    tile[k][tx] = w[(size_t)(k0 + k) * CCn + n0 + tx];
  }
  __syncthreads();
#pragma unroll
  for (int j = 0; j < 4; ++j) {
    int n = ty * 4 + j;
    wt[(size_t)(n0 + n) * CCn + k0 + tx] = bf16_of(tile[tx][n]);
  }
}

// ---------------- V transpose: qkv[B*T][6144] bf16 (V at col 4096) -> Vt[B*H][D][T] ----
__global__ __launch_bounds__(256) void k_vtrans(const short* __restrict__ src,
                                                short* __restrict__ dst) {
  __shared__ short tile[32][33];
  int bh = blockIdx.y, b = bh >> 4, h = bh & 15;
  int dt = blockIdx.x & 3, tt = blockIdx.x >> 2;
  int tx = threadIdx.x & 31, ty = threadIdx.x >> 5;
  const short* sp = src + ((size_t)(b * TT + tt * 32)) * NQKV + 4096 + h * DD + dt * 32;
#pragma unroll
  for (int j = 0; j < 4; ++j) {
    int tr = ty * 4 + j;
    tile[tr][tx] = sp[(size_t)tr * NQKV + tx];
  }
  __syncthreads();
  short* dp = dst + ((size_t)(bh * DD + dt * 32)) * TT + tt * 32;
#pragma unroll
  for (int j = 0; j < 4; ++j) {
    int dr = ty * 4 + j;
    dp[(size_t)dr * TT + tx] = tile[tx][dr];
  }
}

// ---------------- RoPE (Q and K in one launch, y-indexed) ----------------
__global__ __launch_bounds__(256) void k_rope2(const short* __restrict__ qkv,
                                               const float* __restrict__ cosT,
                                               const float* __restrict__ sinT,
                                               short* __restrict__ Qb,
                                               short* __restrict__ Kb, float kmul) {
  int which = blockIdx.y;
  int coff = which << 11;
  short* dstb = which ? Kb : Qb;
  float mul = which ? kmul : 1.0f;
  int idx = blockIdx.x * 256 + threadIdx.x;  // B*T*H*16
  int i4 = (idx & 15) * 4;
  int h = (idx >> 4) & 15;
  int t = (idx >> 8) & 2047;
  int b = idx >> 19;
  const short* row = qkv + ((size_t)(b * TT + t)) * NQKV + coff + h * DD;
  s16x4 v0 = *(const s16x4*)(row + i4);
  s16x4 v1 = *(const s16x4*)(row + i4 + 64);
  f32x4 c4 = *(const f32x4*)(cosT + t * 64 + i4);
  f32x4 s4 = *(const f32x4*)(sinT + t * 64 + i4);
  s16x4 o0, o1;
#pragma unroll
  for (int j = 0; j < 4; ++j) {
    float a = f_of_bf16(v0[j]), bb = f_of_bf16(v1[j]);
    o0[j] = bf16_of((a * c4[j] - bb * s4[j]) * mul);
    o1[j] = bf16_of((bb * c4[j] + a * s4[j]) * mul);
  }
  short* orow = dstb + ((size_t)((b * HH + h) * TT + t)) * DD;
  *(s16x4*)(orow + i4) = o0;
  *(s16x4*)(orow + i4 + 64) = o1;
}

// ---------------- GEMM template: C[M][N] = A[M][K] x Bt[N][K], bf16 in -------------
// BM=128 fixed, BN = BF*64. 512 thr = 8 waves (2M x 4N); per-wave 64 x BF*16.
// LDS: A 4 half-slots (2buf x 2khalf) of 128x32 + B 4 of BN x 32.
// 4 phases/K-tile (ks,bh): {ds_read frags; stage 1 half-tile; barrier;
// setprio MFMA setprio; barrier}; counted vmcnt(1+BSTG) once per K-tile.
// Stage schedule: ph0 A-h1(kt+1,nbuf) | ph1 B-h1(kt+1,nbuf) | ph2 A-h0(kt+2,buf)
// | ph3 B-h0(kt+2,buf). h0 of buf last read ph1 -> ph2/ph3 overwrite safe.
// Queue/K-tile = [Ah1,B*S,Ah0,B*S]; end vmcnt(1+BSTG) drains kt+1-h1, leaves kt+2-h0.
// Tail (kt>=nk-2): vmcnt(0) so last tiles' h1 is guaranteed landed.
template <int BF, int BSTG, bool BF16OUT>
__global__ __launch_bounds__(512) void k_gemmW(const short* __restrict__ A,
                                               const short* __restrict__ Bt,
                                               void* __restrict__ Cout,
                                               int M, int N, int K) {
  constexpr int BN = BF * 64;
  constexpr int AH = 4096;     // shorts per A half (128x32)
  constexpr int BH = BN * 32;  // shorts per B half
  __shared__ short smem[4 * AH + 4 * BH];
  const int tid = threadIdx.x, wid = tid >> 6, lane = tid & 63;
  const int wm = wid >> 2, wn = wid & 3;
  const int lr = lane & 15, lk = lane >> 4;
  const int swz = (lk ^ ((lr >> 1) & 3)) * 8;

  // bijective XCD swizzle (m204); consecutive wg within an XCD chunk share n0.
  int nwg = gridDim.x, orig = blockIdx.x;
  int xcd = orig & 7, bidx = orig >> 3;
  int q = nwg >> 3, rmd = nwg & 7;
  int wg = (xcd < rmd) ? (xcd * (q + 1) + bidx)
                       : (rmd * (q + 1) + (xcd - rmd) * q + bidx);
  const int NBM = M >> 7;
  const int m0 = (wg % NBM) * 128, n0 = (wg / NBM) * BN;

  const int ldswave = (tid & ~63) * 8;  // wave-uniform dest base (shorts)

  auto stageA = [&](int buf, int h, int kt) {
    int rr = tid >> 2, cs = tid & 3;
    int cc = cs ^ ((rr >> 1) & 3);
    lds_load16(A + (size_t)(m0 + rr) * K + kt * 64 + h * 32 + cc * 8,
               smem + buf * 2 * AH + h * AH + ldswave);
  };
  auto stageB = [&](int buf, int h, int kt) {
#pragma unroll
    for (int l = 0; l < BSTG; ++l) {
      int lin = l * 512 + tid;
      int rr = lin >> 2, cs = lin & 3;
      int cc = cs ^ ((rr >> 1) & 3);
      lds_load16(Bt + (size_t)(n0 + rr) * K + kt * 64 + h * 32 + cc * 8,
                 smem + 4 * AH + buf * 2 * BH + h * BH + l * 4096 + ldswave);
    }
  };

  s16x8 af[4], bfr[BF / 2];
  f32x4 acc[4][BF] = {};

#define LOAD_A(ks, buf)                                                        \
  _Pragma("unroll") for (int i = 0; i < 4; ++i) af[i] =                        \
      *(const s16x8*)(smem + (buf) * 2 * AH + (ks) * AH +                      \
                      (wm * 64 + i * 16 + lr) * 32 + swz);
#define LOAD_B(ks, bh, buf)                                                    \
  _Pragma("unroll") for (int j = 0; j < BF / 2; ++j) bfr[j] =                  \
      *(const s16x8*)(smem + 4 * AH + (buf) * 2 * BH + (ks) * BH +             \
                      (wn * (BF * 16) + ((bh) * (BF / 2) + j) * 16 + lr) * 32 +\
                      swz);
#define PHASE_MFMA(bh)                                                         \
  __builtin_amdgcn_s_setprio(1);                                               \
  _Pragma("unroll") for (int i = 0; i < 4; ++i)                                \
      _Pragma("unroll") for (int j = 0; j < BF / 2; ++j)                       \
      acc[i][(bh) * (BF / 2) + j] = __builtin_amdgcn_mfma_f32_16x16x32_bf16(   \
          af[i], bfr[j], acc[i][(bh) * (BF / 2) + j], 0, 0, 0);                \
  __builtin_amdgcn_s_setprio(0);
#define VMCNT_N()                                                              \
  if constexpr (BSTG == 3) asm volatile("s_waitcnt vmcnt(4)" ::: "memory");    \
  else asm volatile("s_waitcnt vmcnt(3)" ::: "memory");

  const int nk = K >> 6;
  // prologue: kt0 full + kt1 h0
  stageA(0, 0, 0);
  stageB(0, 0, 0);
  stageA(0, 1, 0);
  stageB(0, 1, 0);
  stageA(1, 0, 1);
  stageB(1, 0, 1);
  VMCNT_N();
  __builtin_amdgcn_s_barrier();

#pragma unroll 1
  for (int kt = 0; kt < nk; ++kt) {
    const int buf = kt & 1, nbuf = buf ^ 1;
    const bool s1 = (kt + 1 < nk), s2 = (kt + 2 < nk);
    // ph0 (ks0, bh0)
    LOAD_A(0, buf);
    LOAD_B(0, 0, buf);
    if (s1) stageA(nbuf, 1, kt + 1);
    __builtin_amdgcn_s_barrier();
    PHASE_MFMA(0);
    __builtin_amdgcn_s_barrier();
    // ph1 (ks0, bh1)
    LOAD_B(0, 1, buf);
    if (s1) stageB(nbuf, 1, kt + 1);
    __builtin_amdgcn_s_barrier();
    PHASE_MFMA(1);
    __builtin_amdgcn_s_barrier();
    // ph2 (ks1, bh0)
    LOAD_A(1, buf);
    LOAD_B(1, 0, buf);
    if (s2) stageA(buf, 0, kt + 2);
    __builtin_amdgcn_s_barrier();
    PHASE_MFMA(0);
    __builtin_amdgcn_s_barrier();
    // ph3 (ks1, bh1)
    LOAD_B(1, 1, buf);
    if (s2) stageB(buf, 0, kt + 2);
    __builtin_amdgcn_s_barrier();
    PHASE_MFMA(1);
    if (kt < nk - 2) {
      VMCNT_N();
    } else {
      asm volatile("s_waitcnt vmcnt(0)" ::: "memory");
    }
    __builtin_amdgcn_s_barrier();
  }
#undef LOAD_A
#undef LOAD_B
#undef PHASE_MFMA
#undef VMCNT_N

  // epilogue: C frag layout col=lr, row=lk*4+rr (m89)
#pragma unroll
  for (int i = 0; i < 4; ++i)
#pragma unroll
    for (int j = 0; j < BF; ++j) {
      int row0 = m0 + wm * 64 + i * 16 + lk * 4;
      int col = n0 + wn * (BF * 16) + j * 16 + lr;
#pragma unroll
      for (int rr = 0; rr < 4; ++rr) {
        if (BF16OUT)
          ((short*)Cout)[(size_t)(row0 + rr) * N + col] = bf16_of(acc[i][j][rr]);
        else
          ((float*)Cout)[(size_t)(row0 + rr) * N + col] = acc[i][j][rr];
      }
    }
}

// ---------------- Flash attention (unchanged from R2) ----------------
__global__ __launch_bounds__(256) void k_attn(const short* __restrict__ Qb,
                                              const short* __restrict__ Kb,
                                              const short* __restrict__ Vt,
                                              short* __restrict__ yb) {
  __shared__ short Ks[2][64 * 128];
  __shared__ short Vs[128 * 64];
  __shared__ short Ps[4][16 * 72];
  const int tid = threadIdx.x, wid = tid >> 6, lane = tid & 63;
  const int lr = lane & 15, lk = lane >> 4;
  const int bh = blockIdx.y, bx = blockIdx.x;
  const size_t baseQK = (size_t)bh * TT * DD;
  const int b = bh >> 4, h = bh & 15;

  auto stageK = [&](int bi, int kt2) {
#pragma unroll
    for (int it = 0; it < 4; ++it) {
      int ch = it * 256 + tid;
      int r = ch >> 4, cc = ch & 15;
      int cs = cc ^ (r & 7);
      lds_load16(Kb + baseQK + (size_t)(kt2 * 64 + r) * DD + cs * 8,
                 &Ks[bi][(size_t)(it * 256 + wid * 64) * 8]);
    }
  };
  auto stageV = [&](int kt2) {
#pragma unroll
    for (int it = 0; it < 4; ++it) {
      int ch = it * 256 + tid;
      int d = ch >> 3, kc = ch & 7;
      int cs = kc ^ (d & 7);
      lds_load16(Vt + baseQK + (size_t)d * TT + kt2 * 64 + cs * 8,
                 &Vs[(size_t)(it * 256 + wid * 64) * 8]);
    }
  };

#pragma unroll 1
  for (int pass = 0; pass < 2; ++pass) {
    const int qt = pass ? (31 - bx) : bx;
    const int q0 = qt * 64;
    const int qg = q0 + wid * 16 + lr;
    s16x8 qf[4];
#pragma unroll
    for (int ds = 0; ds < 4; ++ds)
      qf[ds] = *(const s16x8*)(Qb + baseQK + (size_t)qg * DD + (ds * 4 + lk) * 8);

    float mrun = -3.0e38f, lrun = 0.f;
    f32x4 yacc[8] = {};

    const int nkt = qt + 1;
    stageK(0, 0);
    stageV(0);
    __syncthreads();
    int buf = 0;
#pragma unroll 1
    for (int kt = 0; kt < nkt; ++kt) {
      if (kt + 1 < nkt) stageK(buf ^ 1, kt + 1);
      f32x4 sf[4] = {};
#pragma unroll
      for (int sub = 0; sub < 4; ++sub) {
        int kr = sub * 16 + lr;
#pragma unroll
        for (int ds = 0; ds < 4; ++ds) {
          int cc = (ds * 4 + lk) ^ (kr & 7);
          s16x8 kf = *(const s16x8*)(&Ks[buf][kr * 128 + cc * 8]);
          sf[sub] = __builtin_amdgcn_mfma_f32_16x16x32_bf16(kf, qf[ds], sf[sub], 0, 0, 0);
        }
      }
      const int kvbase = kt * 64;
      if (kvbase + 63 > q0 + wid * 16) {
#pragma unroll
        for (int sub = 0; sub < 4; ++sub)
#pragma unroll
          for (int r = 0; r < 4; ++r) {
            int kv = kvbase + sub * 16 + lk * 4 + r;
            if (kv > qg) sf[sub][r] = -3.0e38f;
          }
      }
      float tmax = -3.0e38f;
#pragma unroll
      for (int sub = 0; sub < 4; ++sub)
#pragma unroll
        for (int r = 0; r < 4; ++r) tmax = fmaxf(tmax, sf[sub][r]);
      tmax = fmaxf(tmax, __shfl_xor(tmax, 16, 64));
      tmax = fmaxf(tmax, __shfl_xor(tmax, 32, 64));
      if (!__all(tmax <= mrun + 11.0f)) {
        float mnew = fmaxf(mrun, tmax);
        float alpha = ex2(mrun - mnew);
        mrun = mnew;
        lrun *= alpha;
        float ar[4];
#pragma unroll
        for (int r = 0; r < 4; ++r) ar[r] = __shfl(alpha, lk * 4 + r, 64);
#pragma unroll
        for (int dn = 0; dn < 8; ++dn)
#pragma unroll
          for (int r = 0; r < 4; ++r) yacc[dn][r] *= ar[r];
      }
      float psum = 0.f;
#pragma unroll
      for (int sub = 0; sub < 4; ++sub) {
        s16x4 pq;
#pragma unroll
        for (int r = 0; r < 4; ++r) {
          float p = ex2(sf[sub][r] - mrun);
          psum += p;
          pq[r] = bf16_of(p);
        }
        *(s16x4*)(&Ps[wid][lr * 72 + sub * 16 + lk * 4]) = pq;
      }
      psum += __shfl_xor(psum, 16, 64);
      psum += __shfl_xor(psum, 32, 64);
      lrun += psum;
      __syncthreads();
      s16x8 pf0 = *(const s16x8*)(&Ps[wid][lr * 72 + lk * 8]);
      s16x8 pf1 = *(const s16x8*)(&Ps[wid][lr * 72 + 32 + lk * 8]);
#pragma unroll
      for (int dn = 0; dn < 8; ++dn) {
        int d = dn * 16 + lr;
        s16x8 vf0 = *(const s16x8*)(&Vs[d * 64 + (lk ^ (d & 7)) * 8]);
        yacc[dn] = __builtin_amdgcn_mfma_f32_16x16x32_bf16(pf0, vf0, yacc[dn], 0, 0, 0);
        s16x8 vf1 = *(const s16x8*)(&Vs[d * 64 + ((4 + lk) ^ (d & 7)) * 8]);
        yacc[dn] = __builtin_amdgcn_mfma_f32_16x16x32_bf16(pf1, vf1, yacc[dn], 0, 0, 0);
      }
      __syncthreads();
      if (kt + 1 < nkt) stageV(kt + 1);
      buf ^= 1;
    }
    float linv = 1.f / lrun;
    float lr4[4];
#pragma unroll
    for (int r = 0; r < 4; ++r) lr4[r] = __shfl(linv, lk * 4 + r, 64);
#pragma unroll
    for (int dn = 0; dn < 8; ++dn)
#pragma unroll
      for (int r = 0; r < 4; ++r) {
        int t = q0 + wid * 16 + lk * 4 + r;
        int c = h * DD + dn * 16 + lr;
        yb[((size_t)(b * TT + t)) * CCn + c] = bf16_of(yacc[dn][r] * lr4[r]);
      }
  }
}

extern "C" void kernel_launch(void* const* d_in, const int* in_sizes, int n_in,
                              void* d_out, int out_size, void* d_ws, size_t ws_size,
                              hipStream_t stream) {
  const float* x = (const float*)d_in[0];
  const float* wq = (const float*)d_in[1];
  const float* wk = (const float*)d_in[2];
  const float* wv = (const float*)d_in[3];
  const float* wo = (const float*)d_in[4];
  float* out = (float*)d_out;
  char* ws = (char*)d_ws;

  short* xb = (short*)(ws + 0);                 // 16,777,216
  short* wqkvT = (short*)(ws + 16777216);       // [6144][2048] bf16
  short* woT = (short*)(ws + 41943040);
  short* qkv = (short*)(ws + 50331648);         // [4096][6144] bf16
  short* yb = (short*)(ws + 50331648);          // alias: reused after qkv consumed
  short* Qb = (short*)(ws + 100663296);
  short* Kb = (short*)(ws + 117440512);
  short* Vt = (short*)(ws + 134217728);
  float* cosT = (float*)(ws + 150994944);
  float* sinT = (float*)(ws + 151519232);

  const float kmul = 1.4426950408889634f / sqrtf(128.0f);  // log2e / sqrt(D)

  k_tables<<<512, 256, 0, stream>>>(cosT, sinT);
  k_cast_x<<<8192, 256, 0, stream>>>(x, xb);
  k_wtrans4<<<dim3(64, 64, 4), 256, 0, stream>>>(wq, wk, wv, wo, wqkvT, woT);

  // fused QKV GEMM: grid 32x16 = 512 blocks (2 perfect rounds)
  k_gemmW<6, 3, true><<<512, 512, 0, stream>>>(xb, wqkvT, qkv, MMr, NQKV, CCn);

  k_rope2<<<dim3(4096, 2), 256, 0, stream>>>(qkv, cosT, sinT, Qb, Kb, kmul);
  k_vtrans<<<dim3(256, 32), 256, 0, stream>>>(qkv, Vt);

  k_attn<<<dim3(16, 32), 256, 0, stream>>>(Qb, Kb, Vt, yb);

  // output GEMM: grid 32x8 = 256 blocks (1 perfect round), fp32 out
  k_gemmW<4, 2, false><<<256, 512, 0, stream>>>(yb, woT, out, MMr, CCn, CCn);
}